// Round 1
// baseline (158.919 us; speedup 1.0000x reference)
//
#include <hip/hip_runtime.h>

// Problem constants (fixed by the reference setup)
#define B_ 64
#define T_ 32
#define H_ 256
#define HID_ 128
#define NMAX_ 64
#define TILES 2048   // B_ * NMAX_/2 : one tile = 2 (b,l) slots = 64 rows
#define GRID 512
#define BLOCK 256

typedef __attribute__((ext_vector_type(8))) short short8;  // 8 bf16 = 4 VGPRs
typedef __attribute__((ext_vector_type(4))) float f32x4;   // MFMA C/D frag

// float -> bf16 bits, round-to-nearest-even (values are finite here)
__device__ __forceinline__ short f2bf(float f) {
    unsigned u = __builtin_bit_cast(unsigned, f);
    u = (u + 0x7fffu + ((u >> 16) & 1u)) >> 16;
    return (short)u;
}

__global__ __launch_bounds__(BLOCK, 2)
void pe_fused(const float* __restrict__ bbox,
              const float* __restrict__ W1,
              const float* __restrict__ b1,
              const float* __restrict__ W2,
              const float* __restrict__ b2,
              const int*   __restrict__ npf,
              float* __restrict__ out,
              int NT)   // total bbox rows = N*T
{
    __shared__ float W1s[512];     // [4][128]
    __shared__ float b1s[128];
    __shared__ short Hs[64 * 136]; // 64 rows x 128 bf16, stride 136 (16B-aligned pad)

    const int tid  = threadIdx.x;
    const int wave = tid >> 6;
    const int lane = tid & 63;
    const int q    = lane >> 4;   // quad within wave
    const int m16  = lane & 15;

    // Stage W1/b1 into LDS (once per block)
    if (tid < 256) { W1s[tid] = W1[tid]; W1s[tid + 256] = W1[tid + 256]; }
    if (tid < 128) b1s[tid] = b1[tid];

    // B-operand (W2^T) fragments in registers, bf16. Wave w owns cols [64w, 64w+64).
    // Frag layout (verified gemm_bt pattern): lane holds Bt[n = ct*16+m16][k0 .. k0+7],
    // k0 = kc*32 + q*8, i.e. W2[k][n] with k contiguous per lane.
    short8 Bf[4][4];
    float  b2v[4];
#pragma unroll
    for (int ct = 0; ct < 4; ++ct) {
        const int n = wave * 64 + ct * 16 + m16;
        b2v[ct] = b2[n];
#pragma unroll
        for (int kc = 0; kc < 4; ++kc) {
            const int k0 = kc * 32 + q * 8;
            short8 f;
#pragma unroll
            for (int jj = 0; jj < 8; ++jj)
                f[jj] = f2bf(W2[(k0 + jj) * H_ + n]);
            Bf[ct][kc] = f;
        }
    }
    __syncthreads();

    const int r4 = tid >> 2;  // layer-1 row 0..63
    const int c4 = tid & 3;   // layer-1 h-chunk (32 hidden each)

    for (int tt = blockIdx.x; tt < TILES; tt += GRID) {
        const int b  = tt >> 5;
        const int j  = tt & 31;
        const int nb = npf[b];
        const int l0 = 2 * j;

        const int ob0 = (l0 * (B_ * T_) + b * T_) * H_;  // out row (l0,  b, t=0)
        const int ob1 = ob0 + (B_ * T_) * H_;            // out row (l0+1,b, t=0)

        if (l0 >= nb) {
            // Whole tile invalid (block-uniform): zero-fill both 32x256 chunks.
            const int s = r4 >> 5, t = r4 & 31;
            float* dst = out + (s ? ob1 : ob0) + t * H_ + c4 * 64;
            const float4 z = make_float4(0.f, 0.f, 0.f, 0.f);
#pragma unroll
            for (int w = 0; w < 16; ++w)
                *(float4*)(dst + w * 4) = z;
            continue;
        }

        // starts[b] = exclusive cumsum of npf (uniform scalar loop, L2-cached)
        int sb = 0;
        for (int x = 0; x < b; ++x) sb += npf[x];

        // ---- Layer 1: hidden = relu(bbox @ W1 + b1), fp32 -> bf16 into LDS ----
        {
            const int gr = (sb + l0) * T_ + r4;  // global bbox row for local row r4
            float4 bb = make_float4(0.f, 0.f, 0.f, 0.f);
            if (gr < NT) bb = *(const float4*)(bbox + gr * 4);
#pragma unroll
            for (int w = 0; w < 4; ++w) {
                short8 hv;
#pragma unroll
                for (int jj = 0; jj < 8; ++jj) {
                    const int h = c4 * 32 + w * 8 + jj;
                    float v = b1s[h];
                    v = fmaf(bb.x, W1s[h],       v);
                    v = fmaf(bb.y, W1s[128 + h], v);
                    v = fmaf(bb.z, W1s[256 + h], v);
                    v = fmaf(bb.w, W1s[384 + h], v);
                    v = fmaxf(v, 0.f);
                    hv[jj] = f2bf(v);
                }
                *(short8*)&Hs[r4 * 136 + c4 * 32 + w * 8] = hv;
            }
        }
        __syncthreads();

        // ---- Layer 2: 64x256 = (64x128 bf16) @ (128x256 bf16) via MFMA ----
        f32x4 acc[4][4];
#pragma unroll
        for (int rt = 0; rt < 4; ++rt)
#pragma unroll
            for (int ct = 0; ct < 4; ++ct)
                acc[rt][ct] = (f32x4){0.f, 0.f, 0.f, 0.f};

#pragma unroll
        for (int kc = 0; kc < 4; ++kc) {
            short8 a[4];
#pragma unroll
            for (int rt = 0; rt < 4; ++rt)  // A[m=rt*16+m16][k0..k0+7]
                a[rt] = *(const short8*)&Hs[(rt * 16 + m16) * 136 + kc * 32 + q * 8];
#pragma unroll
            for (int rt = 0; rt < 4; ++rt)
#pragma unroll
                for (int ct = 0; ct < 4; ++ct)
                    acc[rt][ct] = __builtin_amdgcn_mfma_f32_16x16x32_bf16(
                        a[rt], Bf[ct][kc], acc[rt][ct], 0, 0, 0);
        }
        __syncthreads();  // Hs consumed; safe for next iteration's writes

        // ---- Epilogue: +b2, validity select, scatter-store ----
        // C/D layout: col = m16 (n within tile), row = q*4 + reg.
        const bool v1 = (l0 + 1) < nb;
#pragma unroll
        for (int rt = 0; rt < 4; ++rt) {
#pragma unroll
            for (int reg = 0; reg < 4; ++reg) {
                const int rl = rt * 16 + q * 4 + reg;  // local row 0..63
                const int s = rl >> 5, t = rl & 31;
                const int base = (s ? ob1 : ob0) + t * H_;
                const bool ok = (s == 0) | v1;
#pragma unroll
                for (int ct = 0; ct < 4; ++ct) {
                    const int h = wave * 64 + ct * 16 + m16;
                    out[base + h] = ok ? (acc[rt][ct][reg] + b2v[ct]) : 0.f;
                }
            }
        }
    }
}

extern "C" void kernel_launch(void* const* d_in, const int* in_sizes, int n_in,
                              void* d_out, int out_size, void* d_ws, size_t ws_size,
                              hipStream_t stream)
{
    const float* bbox = (const float*)d_in[0];
    const float* W1   = (const float*)d_in[1];
    const float* b1   = (const float*)d_in[2];
    const float* W2   = (const float*)d_in[3];
    const float* b2   = (const float*)d_in[4];
    const int*   npf  = (const int*)d_in[5];
    const int NT = in_sizes[0] / 4;  // N*T

    pe_fused<<<GRID, BLOCK, 0, stream>>>(bbox, W1, b1, W2, b2, npf,
                                         (float*)d_out, NT);
}

// Round 2
// 157.164 us; speedup vs baseline: 1.0112x; 1.0112x over previous
//
#include <hip/hip_runtime.h>

// Problem constants (fixed by the reference setup)
#define B_ 64
#define T_ 32
#define H_ 256
#define NMAX_ 64
#define TILES 2048   // B_ * NMAX_/2 : one tile = 2 (b,l) slots = 64 rows
#define GRID 512
#define BLOCK 256

typedef __attribute__((ext_vector_type(8))) short short8;  // 8 bf16 = 4 VGPRs
typedef __attribute__((ext_vector_type(4))) float f32x4;   // MFMA C/D frag

// float -> bf16 bits, round-to-nearest-even (values are finite here)
__device__ __forceinline__ short f2bf(float f) {
    unsigned u = __builtin_bit_cast(unsigned, f);
    u = (u + 0x7fffu + ((u >> 16) & 1u)) >> 16;
    return (short)u;
}

__global__ __launch_bounds__(BLOCK, 2)
void pe_fused(const float* __restrict__ bbox,
              const float* __restrict__ W1,
              const float* __restrict__ b1,
              const float* __restrict__ W2,
              const float* __restrict__ b2,
              const int*   __restrict__ npf,
              float* __restrict__ out,
              int NT)   // total bbox rows = N*T
{
    __shared__ float W1s[512];       // [4][128]
    __shared__ float b1s[128];
    __shared__ int   s_n[64];        // npf[b]
    __shared__ int   s_start[64];    // exclusive cumsum of npf
    __shared__ short Hs[2][64 * 136]; // double-buffered: 64 rows x 128 bf16, stride 136

    const int tid  = threadIdx.x;
    const int wave = tid >> 6;
    const int lane = tid & 63;
    const int q    = lane >> 4;   // quad within wave
    const int m16  = lane & 15;

    // ---- Block setup (once) ----
    if (tid < 256) { W1s[tid] = W1[tid]; W1s[tid + 256] = W1[tid + 256]; }
    if (tid < 128) b1s[tid] = b1[tid];

    // Exclusive prefix sum of npf via wave-0 shuffle scan (replaces the
    // per-tile sequential cumsum loop — that loop was ~3-5k cyc/tile).
    if (wave == 0) {
        int v = npf[lane];
        s_n[lane] = v;
        int s = v;
#pragma unroll
        for (int d = 1; d < 64; d <<= 1) {
            int u = __shfl_up(s, d, 64);
            if (lane >= d) s += u;
        }
        s_start[lane] = s - v;
    }

    // B-operand (W2^T) fragments in registers, bf16. Wave w owns cols [64w, 64w+64).
    short8 Bf[4][4];
    float  b2v[4];
#pragma unroll
    for (int ct = 0; ct < 4; ++ct) {
        const int n = wave * 64 + ct * 16 + m16;
        b2v[ct] = b2[n];
#pragma unroll
        for (int kc = 0; kc < 4; ++kc) {
            const int k0 = kc * 32 + q * 8;
            short8 f;
#pragma unroll
            for (int jj = 0; jj < 8; ++jj)
                f[jj] = f2bf(W2[(k0 + jj) * H_ + n]);
            Bf[ct][kc] = f;
        }
    }
    __syncthreads();   // W1s/b1s/s_n/s_start ready

    const int r4 = tid >> 2;  // layer-1 row 0..63
    const int c4 = tid & 3;   // layer-1 h-chunk (32 hidden each)

    int pbuf = 0;             // Hs parity (flips only on compute tiles)

    for (int tt = blockIdx.x; tt < TILES; tt += GRID) {
        const int b  = tt >> 5;
        const int l0 = (tt & 31) * 2;
        const int nb = s_n[b];

        const int ob0 = (l0 * (B_ * T_) + b * T_) * H_;  // out row (l0,  b, t=0)
        const int ob1 = ob0 + (B_ * T_) * H_;            // out row (l0+1,b, t=0)

        if (l0 >= nb) {
            // Whole tile invalid (block-uniform): zero-fill 64 rows x 1KB.
            // One store instr = one contiguous 1KB row (64 lanes x 16B).
            const float4 z = make_float4(0.f, 0.f, 0.f, 0.f);
#pragma unroll
            for (int rr = 0; rr < 16; ++rr) {
                const int r = rr * 4 + wave;   // wave-uniform row
                float* dst = out + (r < 32 ? ob0 + r * H_ : ob1 + (r - 32) * H_);
                *(float4*)(dst + lane * 4) = z;
            }
            continue;   // no barrier on this path (block-uniform branch)
        }

        const int sb = s_start[b];

        // ---- Layer 1: hidden = relu(bbox @ W1 + b1), fp32 -> bf16 into LDS ----
        {
            const int gr = (sb + l0) * T_ + r4;  // global bbox row for local row r4
            float4 bb = make_float4(0.f, 0.f, 0.f, 0.f);
            if (gr < NT) bb = *(const float4*)(bbox + gr * 4);
            short* hrow = &Hs[pbuf][r4 * 136 + c4 * 32];
#pragma unroll
            for (int w = 0; w < 4; ++w) {
                short8 hv;
#pragma unroll
                for (int jj = 0; jj < 8; ++jj) {
                    const int h = c4 * 32 + w * 8 + jj;
                    float v = b1s[h];
                    v = fmaf(bb.x, W1s[h],       v);
                    v = fmaf(bb.y, W1s[128 + h], v);
                    v = fmaf(bb.z, W1s[256 + h], v);
                    v = fmaf(bb.w, W1s[384 + h], v);
                    v = fmaxf(v, 0.f);
                    hv[jj] = f2bf(v);
                }
                *(short8*)(hrow + w * 8) = hv;
            }
        }
        __syncthreads();   // the ONLY barrier per compute tile (double-buffered Hs)

        // ---- Layer 2: 64x256 = (64x128 bf16) @ (128x256 bf16) via MFMA ----
        f32x4 acc[4][4];
#pragma unroll
        for (int rt = 0; rt < 4; ++rt)
#pragma unroll
            for (int ct = 0; ct < 4; ++ct)
                acc[rt][ct] = (f32x4){0.f, 0.f, 0.f, 0.f};

#pragma unroll
        for (int kc = 0; kc < 4; ++kc) {
            short8 a[4];
#pragma unroll
            for (int rt = 0; rt < 4; ++rt)  // A[m=rt*16+m16][k0..k0+7]
                a[rt] = *(const short8*)&Hs[pbuf][(rt * 16 + m16) * 136 + kc * 32 + q * 8];
#pragma unroll
            for (int rt = 0; rt < 4; ++rt)
#pragma unroll
                for (int ct = 0; ct < 4; ++ct)
                    acc[rt][ct] = __builtin_amdgcn_mfma_f32_16x16x32_bf16(
                        a[rt], Bf[ct][kc], acc[rt][ct], 0, 0, 0);
        }
        pbuf ^= 1;

        // ---- Epilogue: +b2, validity select, scatter-store ----
        // C/D layout: col = m16 (n within tile), row = q*4 + reg.
        const bool v1 = (l0 + 1) < nb;
#pragma unroll
        for (int rt = 0; rt < 4; ++rt) {
#pragma unroll
            for (int reg = 0; reg < 4; ++reg) {
                const int rl = rt * 16 + q * 4 + reg;  // local row 0..63
                const bool ok = (rl < 32) | v1;
                float* dst = out + (rl < 32 ? ob0 + rl * H_ : ob1 + (rl - 32) * H_)
                                 + wave * 64 + m16;
#pragma unroll
                for (int ct = 0; ct < 4; ++ct)
                    dst[ct * 16] = ok ? (acc[rt][ct][reg] + b2v[ct]) : 0.f;
            }
        }
    }
}

extern "C" void kernel_launch(void* const* d_in, const int* in_sizes, int n_in,
                              void* d_out, int out_size, void* d_ws, size_t ws_size,
                              hipStream_t stream)
{
    const float* bbox = (const float*)d_in[0];
    const float* W1   = (const float*)d_in[1];
    const float* b1   = (const float*)d_in[2];
    const float* W2   = (const float*)d_in[3];
    const float* b2   = (const float*)d_in[4];
    const int*   npf  = (const int*)d_in[5];
    const int NT = in_sizes[0] / 4;  // N*T

    pe_fused<<<GRID, BLOCK, 0, stream>>>(bbox, W1, b1, W2, b2, npf,
                                         (float*)d_out, NT);
}

// Round 3
// 153.202 us; speedup vs baseline: 1.0373x; 1.0259x over previous
//
#include <hip/hip_runtime.h>

// Problem constants (fixed by the reference setup)
#define B_ 64
#define T_ 32
#define H_ 256
#define NMAX_ 64
#define TILES 2048   // B_ * NMAX_/2 : one tile = 2 (b,l) slots = 64 rows x 256 cols
#define GRID 512
#define BLOCK 256

typedef __attribute__((ext_vector_type(8))) short short8;  // 8 bf16 = 4 VGPRs
typedef __attribute__((ext_vector_type(4))) float f32x4;   // MFMA C/D frag

// float -> bf16 bits, round-to-nearest-even (values are finite here)
__device__ __forceinline__ short f2bf(float f) {
    unsigned u = __builtin_bit_cast(unsigned, f);
    u = (u + 0x7fffu + ((u >> 16) & 1u)) >> 16;
    return (short)u;
}

// Workgroup barrier WITHOUT the vmcnt(0) store drain __syncthreads would emit.
// LDS visibility needs only lgkmcnt(0); our global stores are fire-and-forget
// (nothing in the kernel ever reads them back).
__device__ __forceinline__ void barrier_nodrain() {
    asm volatile("s_waitcnt lgkmcnt(0)\n\ts_barrier" ::: "memory");
}

__global__ __launch_bounds__(BLOCK, 2)
void pe_fused(const float* __restrict__ bbox,
              const float* __restrict__ W1,
              const float* __restrict__ b1,
              const float* __restrict__ W2,
              const float* __restrict__ b2,
              const int*   __restrict__ npf,
              float* __restrict__ out,
              int NT)   // total bbox rows = N*T
{
    __shared__ float W1s[512];        // [4][128]
    __shared__ float b1s[128];
    __shared__ int   s_n[64];         // npf[b]
    __shared__ int   s_start[64];     // exclusive cumsum of npf
    __shared__ short Hs[2][64 * 136]; // double-buffered: 64 rows x 128 bf16, stride 136

    const int tid  = threadIdx.x;
    const int wave = tid >> 6;
    const int lane = tid & 63;
    const int q    = lane >> 4;   // quad within wave
    const int m16  = lane & 15;

    // ---- Block setup (once) ----
    if (tid < 256) { W1s[tid] = W1[tid]; W1s[tid + 256] = W1[tid + 256]; }
    if (tid < 128) b1s[tid] = b1[tid];

    // Exclusive prefix sum of npf via wave-0 shuffle scan.
    if (wave == 0) {
        int v = npf[lane];
        s_n[lane] = v;
        int s = v;
#pragma unroll
        for (int d = 1; d < 64; d <<= 1) {
            int u = __shfl_up(s, d, 64);
            if (lane >= d) s += u;
        }
        s_start[lane] = s - v;
    }

    // W2^T fragments in registers, bf16. Wave w owns output cols [64w, 64w+64).
    // Lane holds W2[k = kc*32 + q*8 + j][wave*64 + ct*16 + m16] — this register
    // content is valid BOTH as a B-operand (n=m16) and as an A-operand (m=m16).
    // We use it as the A operand so D comes out with 4 consecutive h per lane.
    short8 Wf[4][4];
    float4 b2q[4];
#pragma unroll
    for (int ct = 0; ct < 4; ++ct) {
        b2q[ct] = *(const float4*)(b2 + wave * 64 + ct * 16 + q * 4);
#pragma unroll
        for (int kc = 0; kc < 4; ++kc) {
            const int k0 = kc * 32 + q * 8;
            short8 f;
#pragma unroll
            for (int jj = 0; jj < 8; ++jj)
                f[jj] = f2bf(W2[(k0 + jj) * H_ + wave * 64 + ct * 16 + m16]);
            Wf[ct][kc] = f;
        }
    }
    __syncthreads();   // W1s/b1s/s_n/s_start ready (no stores outstanding yet)

    const int r4 = tid >> 2;  // layer-1 row 0..63
    const int c4 = tid & 3;   // layer-1 h-chunk (32 hidden each)

    // ---- Preload ALL 4 tiles' bbox rows (no global loads inside the loop;
    // nothing later ever waits behind the epilogue stores in the vmcnt queue).
    float4 bb[4];
#pragma unroll
    for (int i = 0; i < 4; ++i) {
        const int tt = blockIdx.x + i * GRID;
        const int b  = tt >> 5;
        const int l0 = (tt & 31) * 2;
        const int g  = (s_start[b] + l0) * T_ + r4;
        bb[i] = make_float4(0.f, 0.f, 0.f, 0.f);
        if (g < NT) bb[i] = *(const float4*)(bbox + g * 4);
    }

    int pbuf = 0;  // Hs parity — flips on compute tiles only (2 barriers between
                   // any write of buf p and the previous read of buf p)

#pragma unroll
    for (int i = 0; i < 4; ++i) {
        const int tt = blockIdx.x + i * GRID;
        const int b  = tt >> 5;
        const int l0 = (tt & 31) * 2;
        const int nb = s_n[b];

        const int ob0 = (l0 * (B_ * T_) + b * T_) * H_;  // out row (l0,  b, t=0)
        const int ob1 = ob0 + (B_ * T_) * H_;            // out row (l0+1,b, t=0)

        if (l0 >= nb) {
            // Whole tile invalid (block-uniform): zero-fill 64 rows x 1KB,
            // one store instr = one contiguous 1KB row (64 lanes x 16B).
            const float4 z = make_float4(0.f, 0.f, 0.f, 0.f);
#pragma unroll
            for (int rr = 0; rr < 16; ++rr) {
                const int r = rr * 4 + wave;   // wave-uniform row
                float* dst = out + (r < 32 ? ob0 + r * H_ : ob1 + (r - 32) * H_);
                *(float4*)(dst + lane * 4) = z;
            }
            continue;   // block-uniform branch; no barrier on this path
        }

        // ---- Layer 1: hidden = relu(bbox @ W1 + b1), fp32 -> bf16 into LDS ----
        {
            const float4 bv = bb[i];
            short* hrow = &Hs[pbuf][r4 * 136 + c4 * 32];
#pragma unroll
            for (int w = 0; w < 4; ++w) {
                short8 hv;
#pragma unroll
                for (int jj = 0; jj < 8; ++jj) {
                    const int h = c4 * 32 + w * 8 + jj;
                    float v = b1s[h];
                    v = fmaf(bv.x, W1s[h],       v);
                    v = fmaf(bv.y, W1s[128 + h], v);
                    v = fmaf(bv.z, W1s[256 + h], v);
                    v = fmaf(bv.w, W1s[384 + h], v);
                    v = fmaxf(v, 0.f);
                    hv[jj] = f2bf(v);
                }
                *(short8*)(hrow + w * 8) = hv;
            }
        }
        barrier_nodrain();   // lgkmcnt(0) + s_barrier — NO vmcnt store drain

        // ---- Layer 2 (transposed orientation): D[m=h][n=row] = W2^T x H^T ----
        f32x4 acc[4][4];   // [ct][rt]
#pragma unroll
        for (int ct = 0; ct < 4; ++ct)
#pragma unroll
            for (int rt = 0; rt < 4; ++rt)
                acc[ct][rt] = (f32x4){0.f, 0.f, 0.f, 0.f};

#pragma unroll
        for (int kc = 0; kc < 4; ++kc) {
            short8 hf[4];
#pragma unroll
            for (int rt = 0; rt < 4; ++rt)  // B-operand: H[n=rt*16+m16][k0..k0+7]
                hf[rt] = *(const short8*)&Hs[pbuf][(rt * 16 + m16) * 136 + kc * 32 + q * 8];
#pragma unroll
            for (int ct = 0; ct < 4; ++ct)
#pragma unroll
                for (int rt = 0; rt < 4; ++rt)
                    acc[ct][rt] = __builtin_amdgcn_mfma_f32_16x16x32_bf16(
                        Wf[ct][kc], hf[rt], acc[ct][rt], 0, 0, 0);
        }
        pbuf ^= 1;

        // ---- Epilogue: +b2, validity select, float4 stores ----
        // D layout: n(col)=m16 -> output row rt*16+m16; m(row)=q*4+reg -> h.
        // Lane's 4 regs = 4 consecutive h -> one dwordx4 store per (rt,ct).
        const bool v1 = (l0 + 1) < nb;
#pragma unroll
        for (int rt = 0; rt < 4; ++rt) {
            const int rl = rt * 16 + m16;            // local row 0..63
            const bool ok = (rt < 2) | v1;           // rt<2 <=> rl<32 (slot l0)
            float* base = out + (rt < 2 ? ob0 + rl * H_ : ob1 + (rl - 32) * H_)
                              + wave * 64 + q * 4;
#pragma unroll
            for (int ct = 0; ct < 4; ++ct) {
                const f32x4 d = acc[ct][rt];
                float4 v = make_float4(0.f, 0.f, 0.f, 0.f);
                if (ok) v = make_float4(d[0] + b2q[ct].x, d[1] + b2q[ct].y,
                                        d[2] + b2q[ct].z, d[3] + b2q[ct].w);
                *(float4*)(base + ct * 16) = v;
            }
        }
    }
}

extern "C" void kernel_launch(void* const* d_in, const int* in_sizes, int n_in,
                              void* d_out, int out_size, void* d_ws, size_t ws_size,
                              hipStream_t stream)
{
    const float* bbox = (const float*)d_in[0];
    const float* W1   = (const float*)d_in[1];
    const float* b1   = (const float*)d_in[2];
    const float* W2   = (const float*)d_in[3];
    const float* b2   = (const float*)d_in[4];
    const int*   npf  = (const int*)d_in[5];
    const int NT = in_sizes[0] / 4;  // N*T

    pe_fused<<<GRID, BLOCK, 0, stream>>>(bbox, W1, b1, W2, b2, npf,
                                         (float*)d_out, NT);
}

// Round 4
// 153.084 us; speedup vs baseline: 1.0381x; 1.0008x over previous
//
#include <hip/hip_runtime.h>

// Problem constants (fixed by the reference setup)
#define B_ 64
#define T_ 32
#define H_ 256
#define NMAX_ 64
#define TILES 2048   // B_ * NMAX_/2 : one tile = 2 (b,l) slots = 64 rows x 256 cols
#define GRID 512
#define BLOCK 256
#define SROW 260     // staging row stride in dwords (256 + 4 pad -> bank-balanced)

typedef __attribute__((ext_vector_type(8))) short short8;  // 8 bf16 = 4 VGPRs
typedef __attribute__((ext_vector_type(4))) float f32x4;   // MFMA C/D frag

// float -> bf16 bits, round-to-nearest-even (values are finite here)
__device__ __forceinline__ short f2bf(float f) {
    unsigned u = __builtin_bit_cast(unsigned, f);
    u = (u + 0x7fffu + ((u >> 16) & 1u)) >> 16;
    return (short)u;
}

// Workgroup barrier WITHOUT the vmcnt(0) store drain __syncthreads would emit.
// LDS visibility needs only lgkmcnt(0); global stores are fire-and-forget.
__device__ __forceinline__ void barrier_nodrain() {
    asm volatile("s_waitcnt lgkmcnt(0)\n\ts_barrier" ::: "memory");
}

__global__ __launch_bounds__(BLOCK, 2)
void pe_fused(const float* __restrict__ bbox,
              const float* __restrict__ W1,
              const float* __restrict__ b1,
              const float* __restrict__ W2,
              const float* __restrict__ b2,
              const int*   __restrict__ npf,
              float* __restrict__ out,
              int NT)   // total bbox rows = N*T
{
    __shared__ float W1s[512];        // [4][128]
    __shared__ float b1s[128];
    __shared__ int   s_n[64];         // npf[b]
    __shared__ int   s_start[64];     // exclusive cumsum of npf
    __shared__ short Hs[64 * 136];    // 64 rows x 128 bf16, stride 136 (single buffer)
    __shared__ float stage[32 * SROW];// 32 output rows staged for full-line stores

    const int tid  = threadIdx.x;
    const int wave = tid >> 6;
    const int lane = tid & 63;
    const int q    = lane >> 4;   // quad within wave
    const int m16  = lane & 15;

    // ---- Block setup (once) ----
    if (tid < 256) { W1s[tid] = W1[tid]; W1s[tid + 256] = W1[tid + 256]; }
    if (tid < 128) b1s[tid] = b1[tid];

    // Exclusive prefix sum of npf via wave-0 shuffle scan.
    if (wave == 0) {
        int v = npf[lane];
        s_n[lane] = v;
        int s = v;
#pragma unroll
        for (int d = 1; d < 64; d <<= 1) {
            int u = __shfl_up(s, d, 64);
            if (lane >= d) s += u;
        }
        s_start[lane] = s - v;
    }

    // W2^T fragments in registers, bf16. Wave w owns output cols [64w, 64w+64).
    // Used as the A operand so D gives each lane 4 consecutive h (= q*4+reg).
    short8 Wf[4][4];
    float4 b2q[4];
#pragma unroll
    for (int ct = 0; ct < 4; ++ct) {
        b2q[ct] = *(const float4*)(b2 + wave * 64 + ct * 16 + q * 4);
#pragma unroll
        for (int kc = 0; kc < 4; ++kc) {
            const int k0 = kc * 32 + q * 8;
            short8 f;
#pragma unroll
            for (int jj = 0; jj < 8; ++jj)
                f[jj] = f2bf(W2[(k0 + jj) * H_ + wave * 64 + ct * 16 + m16]);
            Wf[ct][kc] = f;
        }
    }
    __syncthreads();   // W1s/b1s/s_n/s_start ready

    const int r4 = tid >> 2;  // layer-1 row 0..63
    const int c4 = tid & 3;   // layer-1 h-chunk (32 hidden each)

    // ---- Preload ALL 4 tiles' bbox rows (no global loads inside the loop).
    float4 bb[4];
#pragma unroll
    for (int i = 0; i < 4; ++i) {
        const int tt = blockIdx.x + i * GRID;
        const int b  = tt >> 5;
        const int l0 = (tt & 31) * 2;
        const int g  = (s_start[b] + l0) * T_ + r4;
        bb[i] = make_float4(0.f, 0.f, 0.f, 0.f);
        if (g < NT) bb[i] = *(const float4*)(bbox + g * 4);
    }

#pragma unroll
    for (int i = 0; i < 4; ++i) {
        const int tt = blockIdx.x + i * GRID;
        const int b  = tt >> 5;
        const int l0 = (tt & 31) * 2;
        const int nb = s_n[b];

        const int ob0 = (l0 * (B_ * T_) + b * T_) * H_;  // out row (l0,  b, t=0)
        const int ob1 = ob0 + (B_ * T_) * H_;            // out row (l0+1,b, t=0)

        if (l0 >= nb) {
            // Whole tile invalid (block-uniform): zero-fill 64 rows x 1KB,
            // one store instr = one contiguous 1KB row (full-line requests).
            const float4 z = make_float4(0.f, 0.f, 0.f, 0.f);
#pragma unroll
            for (int rr = 0; rr < 16; ++rr) {
                const int r = rr * 4 + wave;   // wave-uniform row
                float* dst = out + (r < 32 ? ob0 + r * H_ : ob1 + (r - 32) * H_);
                *(float4*)(dst + lane * 4) = z;
            }
            continue;   // block-uniform branch; no barrier on this path
        }

        // ---- Layer 1: hidden = relu(bbox @ W1 + b1), fp32 -> bf16 into LDS ----
        {
            const float4 bv = bb[i];
            short* hrow = &Hs[r4 * 136 + c4 * 32];
#pragma unroll
            for (int w = 0; w < 4; ++w) {
                short8 hv;
#pragma unroll
                for (int jj = 0; jj < 8; ++jj) {
                    const int h = c4 * 32 + w * 8 + jj;
                    float v = b1s[h];
                    v = fmaf(bv.x, W1s[h],       v);
                    v = fmaf(bv.y, W1s[128 + h], v);
                    v = fmaf(bv.z, W1s[256 + h], v);
                    v = fmaf(bv.w, W1s[384 + h], v);
                    v = fmaxf(v, 0.f);
                    hv[jj] = f2bf(v);
                }
                *(short8*)(hrow + w * 8) = hv;
            }
        }
        barrier_nodrain();

        // ---- Layer 2 (transposed orientation): D[m=h][n=row] = W2^T x H^T ----
        f32x4 acc[4][4];   // [ct][rt]
#pragma unroll
        for (int ct = 0; ct < 4; ++ct)
#pragma unroll
            for (int rt = 0; rt < 4; ++rt)
                acc[ct][rt] = (f32x4){0.f, 0.f, 0.f, 0.f};

#pragma unroll
        for (int kc = 0; kc < 4; ++kc) {
            short8 hf[4];
#pragma unroll
            for (int rt = 0; rt < 4; ++rt)  // B-operand: H[n=rt*16+m16][k0..k0+7]
                hf[rt] = *(const short8*)&Hs[(rt * 16 + m16) * 136 + kc * 32 + q * 8];
#pragma unroll
            for (int ct = 0; ct < 4; ++ct)
#pragma unroll
                for (int rt = 0; rt < 4; ++rt)
                    acc[ct][rt] = __builtin_amdgcn_mfma_f32_16x16x32_bf16(
                        Wf[ct][kc], hf[rt], acc[ct][rt], 0, 0, 0);
        }
        // (Hs reads are drained by the next lgkm barrier -> single Hs buffer is safe)

        // ---- Epilogue: +b2, LDS-transpose 32 rows at a time, full-row stores ----
        // acc[ct][rt]: output row rt*16+m16, h = wave*64 + ct*16 + q*4 + [0,4).
        const bool v1 = (l0 + 1) < nb;
#pragma unroll
        for (int half = 0; half < 2; ++half) {
            const int obh = half ? ob1 : ob0;
            if (half == 1 && !v1) {
                // Invalid slot l0+1 (block-uniform): store zeros, skip staging.
                const float4 z = make_float4(0.f, 0.f, 0.f, 0.f);
#pragma unroll
                for (int j = 0; j < 8; ++j)
                    *(float4*)(out + obh + (wave * 8 + j) * H_ + lane * 4) = z;
                continue;
            }
            // Stage rows [32*half, 32*half+32): rt = 2*half + {0,1}
#pragma unroll
            for (int rt2 = 0; rt2 < 2; ++rt2) {
                const int rt = 2 * half + rt2;
                const int u  = rt2 * 16 + m16;       // row within half
#pragma unroll
                for (int ct = 0; ct < 4; ++ct) {
                    const f32x4 d = acc[ct][rt];
                    float4 v = make_float4(d[0] + b2q[ct].x, d[1] + b2q[ct].y,
                                           d[2] + b2q[ct].z, d[3] + b2q[ct].w);
                    *(float4*)&stage[u * SROW + wave * 64 + ct * 16 + q * 4] = v;
                }
            }
            barrier_nodrain();
            // Store: one instruction = one full 1KB row (64 lanes x 16B).
#pragma unroll
            for (int j = 0; j < 8; ++j) {
                const int u = wave * 8 + j;
                const float4 v = *(const float4*)&stage[u * SROW + lane * 4];
                *(float4*)(out + obh + u * H_ + lane * 4) = v;
            }
            barrier_nodrain();   // stage reusable (also orders Hs for next tile)
        }
    }
}

extern "C" void kernel_launch(void* const* d_in, const int* in_sizes, int n_in,
                              void* d_out, int out_size, void* d_ws, size_t ws_size,
                              hipStream_t stream)
{
    const float* bbox = (const float*)d_in[0];
    const float* W1   = (const float*)d_in[1];
    const float* b1   = (const float*)d_in[2];
    const float* W2   = (const float*)d_in[3];
    const float* b2   = (const float*)d_in[4];
    const int*   npf  = (const int*)d_in[5];
    const int NT = in_sizes[0] / 4;  // N*T

    pe_fused<<<GRID, BLOCK, 0, stream>>>(bbox, W1, b1, W2, b2, npf,
                                         (float*)d_out, NT);
}